// Round 1
// baseline (358.166 us; speedup 1.0000x reference)
//
#include <hip/hip_runtime.h>
#include <math.h>

typedef float fx4 __attribute__((ext_vector_type(4)));
typedef short bf8 __attribute__((ext_vector_type(8)));
typedef unsigned short us4 __attribute__((ext_vector_type(4)));

#define DEV __device__ __forceinline__

static constexpr int BB = 2;
static constexpr int SS = 1024;
static constexpr int II = 2048;
static constexpr int NSt = 16;
static constexpr int MR = BB * SS;   // 2048 rows
static constexpr int NC = 32;        // scan chunks
static constexpr int CL = SS / NC;   // 32 steps per chunk

DEV unsigned short f2bf(float f) {
  union { float f; unsigned u; } v; v.f = f;
  return (unsigned short)((v.u + 0x7FFFu + ((v.u >> 16) & 1u)) >> 16);
}

DEV float fsilu(float x) { return x / (1.f + __expf(-x)); }

// ---------- cast fp32 -> bf16 (contiguous, 4 elems/thread) ----------
__global__ void k_cast(const float* __restrict__ in, unsigned short* __restrict__ o, int n4) {
  int t = blockIdx.x * blockDim.x + threadIdx.x;
  if (t >= n4) return;
  fx4 v = *(const fx4*)(in + (size_t)t * 4);
  us4 r; r.x = f2bf(v.x); r.y = f2bf(v.y); r.z = f2bf(v.z); r.w = f2bf(v.w);
  *(us4*)(o + (size_t)t * 4) = r;
}

// ---------- transpose + cast: W[K][N] f32 -> Wt[N][K] bf16 ----------
template<int K, int N>
__global__ __launch_bounds__(256) void k_transpose_cast(const float* __restrict__ W,
                                                        unsigned short* __restrict__ Wt) {
  __shared__ float tile[64][65];
  int tk0 = blockIdx.y * 64, tn0 = blockIdx.x * 64;
  int t = threadIdx.x;
  int r = t >> 4, c4 = (t & 15) * 4;
#pragma unroll
  for (int q = 0; q < 4; ++q) {
    fx4 v = *(const fx4*)(W + (size_t)(tk0 + r + q * 16) * N + tn0 + c4);
    tile[r + q * 16][c4 + 0] = v.x;
    tile[r + q * 16][c4 + 1] = v.y;
    tile[r + q * 16][c4 + 2] = v.z;
    tile[r + q * 16][c4 + 3] = v.w;
  }
  __syncthreads();
#pragma unroll
  for (int q = 0; q < 4; ++q) {
    int nn = r + q * 16;
    us4 o;
    o.x = f2bf(tile[c4 + 0][nn]);
    o.y = f2bf(tile[c4 + 1][nn]);
    o.z = f2bf(tile[c4 + 2][nn]);
    o.w = f2bf(tile[c4 + 3][nn]);
    *(us4*)(Wt + (size_t)(tn0 + nn) * K + tk0 + c4) = o;
  }
}

// ---------- bf16 MFMA GEMM: C[M][N] = A[M][K] * Bt[N][K]^T ----------
// EPI 0: plain f32 store.  EPI 1: softplus(acc + bias[col]).
template<int M, int N, int K, int EPI>
__global__ __launch_bounds__(256) void k_gemm(const unsigned short* __restrict__ A,
                                              const unsigned short* __restrict__ Bt,
                                              const float* __restrict__ bias,
                                              float* __restrict__ C) {
  constexpr int LDT = 40;  // 32 + 8 pad (elements)
  __shared__ __align__(16) unsigned short As[128 * LDT];
  __shared__ __align__(16) unsigned short Bs[128 * LDT];
  const int t = threadIdx.x;
  const int bm0 = blockIdx.y * 128, bn0 = blockIdx.x * 128;
  const int w = t >> 6, l = t & 63;
  const int wm = (w >> 1) * 64, wn = (w & 1) * 64;
  const int lr = l & 15, lg = l >> 4;
  const int srow = t >> 1, sseg = (t & 1) * 16;

  fx4 acc[4][4] = {};

  const unsigned short* ga = A + (size_t)(bm0 + srow) * K + sseg;
  const unsigned short* gb = Bt + (size_t)(bn0 + srow) * K + sseg;
  unsigned short* la = &As[srow * LDT + sseg];
  unsigned short* lb = &Bs[srow * LDT + sseg];

  for (int k0 = 0; k0 < K; k0 += 32) {
    fx4 va0 = *(const fx4*)(ga + k0);
    fx4 va1 = *(const fx4*)(ga + k0 + 8);
    fx4 vb0 = *(const fx4*)(gb + k0);
    fx4 vb1 = *(const fx4*)(gb + k0 + 8);
    *(fx4*)(la) = va0;  *(fx4*)(la + 8) = va1;
    *(fx4*)(lb) = vb0;  *(fx4*)(lb + 8) = vb1;
    __syncthreads();
    bf8 af[4], bg[4];
#pragma unroll
    for (int m = 0; m < 4; ++m) af[m] = *(const bf8*)(&As[(wm + m * 16 + lr) * LDT + lg * 8]);
#pragma unroll
    for (int n = 0; n < 4; ++n) bg[n] = *(const bf8*)(&Bs[(wn + n * 16 + lr) * LDT + lg * 8]);
#pragma unroll
    for (int m = 0; m < 4; ++m)
#pragma unroll
      for (int n = 0; n < 4; ++n)
        acc[m][n] = __builtin_amdgcn_mfma_f32_16x16x32_bf16(af[m], bg[n], acc[m][n], 0, 0, 0);
    __syncthreads();
  }
#pragma unroll
  for (int m = 0; m < 4; ++m) {
#pragma unroll
    for (int n = 0; n < 4; ++n) {
      int col = bn0 + wn + n * 16 + lr;
#pragma unroll
      for (int r = 0; r < 4; ++r) {
        int row = bm0 + wm + m * 16 + lg * 4 + r;
        float v = acc[m][n][r];
        if constexpr (EPI == 1) {
          float xx = v + bias[col];
          v = (xx > 20.f) ? xx : log1pf(__expf(xx));
        }
        C[(size_t)row * N + col] = v;
      }
    }
  }
}

// ---------- depthwise conv (k=3, pad 1 per batch) + silu ----------
__global__ void k_conv(const float* __restrict__ zx, const float* __restrict__ cw,
                       const float* __restrict__ cb, float* __restrict__ hf,
                       unsigned short* __restrict__ hb) {
  int idx = blockIdx.x * blockDim.x + threadIdx.x;  // MR * II/4 threads
  int i4 = idx & (II / 4 - 1);
  int r = idx >> 9;
  int s = r & (SS - 1);
  int i = i4 * 4;
  const float* base = zx + (size_t)r * (2 * II) + i;
  fx4 cur = *(const fx4*)(base);
  fx4 lf = {0.f, 0.f, 0.f, 0.f}, rt = {0.f, 0.f, 0.f, 0.f};
  if (s > 0)      lf = *(const fx4*)(base - 2 * II);
  if (s < SS - 1) rt = *(const fx4*)(base + 2 * II);
  fx4 hv; us4 hbv;
#pragma unroll
  for (int j = 0; j < 4; ++j) {
    float w0 = cw[(i + j) * 3 + 0], w1 = cw[(i + j) * 3 + 1], w2 = cw[(i + j) * 3 + 2];
    float c = lf[j] * w0 + cur[j] * w1 + rt[j] * w2 + cb[i + j];
    float h = fsilu(c);
    hv[j] = h; hbv[j] = f2bf(h);
  }
  *(fx4*)(hf + (size_t)r * II + i) = hv;
  *(us4*)(hb + (size_t)r * II + i) = hbv;
}

// ---------- B_mat = h @ W_state[:,16:32]  (one wave per row) ----------
__global__ __launch_bounds__(256) void k_state(const float* __restrict__ h,
                                               const float* __restrict__ Ws,
                                               float* __restrict__ Bm) {
  int wv = blockIdx.x * 4 + (threadIdx.x >> 6);
  int l = threadIdx.x & 63;
  int n = l & 15, ks = l >> 4;
  const float* hr = h + (size_t)wv * II;
  float acc = 0.f;
#pragma unroll 4
  for (int j = 0; j < II / 4; ++j) {
    int k = ks * (II / 4) + j;
    acc = fmaf(hr[k], Ws[k * (2 * NSt) + NSt + n], acc);
  }
  acc += __shfl_xor(acc, 16);
  acc += __shfl_xor(acc, 32);
  if (ks == 0) Bm[(size_t)wv * NSt + n] = acc;
}

// ---------- scan pass 1: per-chunk local scan from zero ----------
__global__ void k_scan1(const float* __restrict__ dt, const float* __restrict__ h,
                        const float* __restrict__ Bm, const float* __restrict__ Alog,
                        float* __restrict__ me, float* __restrict__ pa) {
  int t = threadIdx.x;
  int n = t & 15, il = t >> 4;
  int blk = blockIdx.x;
  int itile = blk & (II / 16 - 1);
  int bc = blk >> 7;
  int c = bc & (NC - 1);
  int b = bc >> 5;
  int i = itile * 16 + il;
  float a = -__expf(Alog[i * NSt + n]);
  float mem = 0.f, prod = 1.f;
  int s0 = c * CL;
  for (int q = 0; q < CL; ++q) {
    size_t ro = (size_t)(b * SS + s0 + q);
    float dtv = dt[ro * II + i];
    float hv = h[ro * II + i];
    float bm = Bm[ro * NSt + n];
    float dA = __expf(dtv * a);
    mem = fmaf(dA, mem, dtv * bm * hv);
    prod *= dA;
  }
  size_t o = (((size_t)b * NC + c) << 15) + ((size_t)i * 16 + n);
  me[o] = mem; pa[o] = prod;
}

// ---------- scan pass 2: carry combine across chunks ----------
__global__ void k_scan2(const float* __restrict__ me, const float* __restrict__ pa,
                        float* __restrict__ carry) {
  int idx = blockIdx.x * blockDim.x + threadIdx.x;  // BB*II*16 = 65536
  int b = idx >> 15;
  int rem = idx & 32767;
  float cur = 0.f;
  for (int c = 0; c < NC; ++c) {
    size_t o = (((size_t)b * NC + c) << 15) + rem;
    carry[o] = cur;
    cur = fmaf(pa[o], cur, me[o]);
  }
}

// ---------- scan pass 3: replay with carry, y = sum_n mem + skip*h, fuse gate ----------
__global__ void k_scan3(const float* __restrict__ dt, const float* __restrict__ h,
                        const float* __restrict__ Bm, const float* __restrict__ Alog,
                        const float* __restrict__ carry, const float* __restrict__ skip,
                        const float* __restrict__ zx, unsigned short* __restrict__ yg) {
  int t = threadIdx.x;
  int n = t & 15, il = t >> 4;
  int blk = blockIdx.x;
  int itile = blk & (II / 16 - 1);
  int bc = blk >> 7;
  int c = bc & (NC - 1);
  int b = bc >> 5;
  int i = itile * 16 + il;
  float a = -__expf(Alog[i * NSt + n]);
  size_t cidx = (((size_t)b * NC + c) << 15) + ((size_t)i * 16 + n);
  float mem = carry[cidx];
  float sk = skip[i];
  int s0 = c * CL;
  for (int q = 0; q < CL; ++q) {
    size_t ro = (size_t)(b * SS + s0 + q);
    float dtv = dt[ro * II + i];
    float hv = h[ro * II + i];
    float bm = Bm[ro * NSt + n];
    float dA = __expf(dtv * a);
    mem = fmaf(dA, mem, dtv * bm * hv);
    float y = mem;
    y += __shfl_xor(y, 1);
    y += __shfl_xor(y, 2);
    y += __shfl_xor(y, 4);
    y += __shfl_xor(y, 8);
    if (n == 0) {
      y += sk * hv;
      float g = zx[ro * (2 * II) + II + i];
      yg[ro * II + i] = f2bf(y * fsilu(g));
    }
  }
}

extern "C" void kernel_launch(void* const* d_in, const int* in_sizes, int n_in,
                              void* d_out, int out_size, void* d_ws, size_t ws_size,
                              hipStream_t stream) {
  const float* x      = (const float*)d_in[0];
  const float* W_in   = (const float*)d_in[1];
  const float* conv_w = (const float*)d_in[2];
  const float* conv_b = (const float*)d_in[3];
  const float* W_state= (const float*)d_in[4];
  const float* W_time = (const float*)d_in[5];
  const float* b_time = (const float*)d_in[6];
  const float* A_log  = (const float*)d_in[7];
  const float* skip   = (const float*)d_in[8];
  const float* W_out  = (const float*)d_in[9];
  float* out = (float*)d_out;

  char* p = (char*)d_ws;
  const size_t MB = 1u << 20;
  unsigned short* W_in_t   = (unsigned short*)(p + 0);        // 8 MiB  [reused: memend]
  unsigned short* W_time_t = (unsigned short*)(p + 8 * MB);   // 8 MiB  [reused: carry]
  unsigned short* W_out_t  = (unsigned short*)(p + 16 * MB);  // 4 MiB
  unsigned short* x_bf     = (unsigned short*)(p + 20 * MB);  // 4 MiB
  float*          zx       = (float*)(p + 24 * MB);           // 32 MiB
  float*          hf       = (float*)(p + 56 * MB);           // 16 MiB
  unsigned short* h_bf     = (unsigned short*)(p + 72 * MB);  // 8 MiB  [reused: yg]
  float*          dtb      = (float*)(p + 80 * MB);           // 16 MiB
  float*          Bm       = (float*)(p + 96 * MB);           // 128 KiB
  float*          pa       = (float*)(p + 97 * MB);           // 8 MiB (prodA)  -> total 105 MiB
  float* me    = (float*)W_in_t;    // alias, live after GEMM1 is done with W_in_t
  float* carry = (float*)W_time_t;  // alias, live after dt-GEMM is done with W_time_t
  unsigned short* yg = h_bf;        // alias, live after dt-GEMM is done with h_bf

  // 1) casts / transposes
  k_cast<<<dim3((MR * 1024 / 4 + 255) / 256), 256, 0, stream>>>(x, x_bf, MR * 1024 / 4);
  k_transpose_cast<1024, 4096><<<dim3(64, 16), 256, 0, stream>>>(W_in, W_in_t);
  k_transpose_cast<2048, 2048><<<dim3(32, 32), 256, 0, stream>>>(W_time, W_time_t);
  k_transpose_cast<2048, 1024><<<dim3(16, 32), 256, 0, stream>>>(W_out, W_out_t);

  // 2) zx = x @ W_in   [2048 x 4096] f32
  k_gemm<2048, 4096, 1024, 0><<<dim3(32, 16), 256, 0, stream>>>(x_bf, W_in_t, nullptr, zx);

  // 3) conv + silu -> h (f32 + bf16)
  k_conv<<<dim3(MR * (II / 4) / 256), 256, 0, stream>>>(zx, conv_w, conv_b, hf, h_bf);

  // 4) B_mat = h @ W_state[:,16:32]
  k_state<<<dim3(MR / 4), 256, 0, stream>>>(hf, W_state, Bm);

  // 5) dt = softplus(h @ W_time + b_time)
  k_gemm<2048, 2048, 2048, 1><<<dim3(16, 16), 256, 0, stream>>>(h_bf, W_time_t, b_time, dtb);

  // 6) chunked selective scan
  k_scan1<<<dim3(BB * NC * (II / 16)), 256, 0, stream>>>(dtb, hf, Bm, A_log, me, pa);
  k_scan2<<<dim3(BB * II * 16 / 256), 256, 0, stream>>>(me, pa, carry);
  k_scan3<<<dim3(BB * NC * (II / 16)), 256, 0, stream>>>(dtb, hf, Bm, A_log, carry, skip, zx, yg);

  // 7) out = (y * silu(gate)) @ W_out
  k_gemm<2048, 1024, 2048, 0><<<dim3(8, 16), 256, 0, stream>>>(yg, W_out_t, nullptr, out);
}

// Round 2
// 258.141 us; speedup vs baseline: 1.3875x; 1.3875x over previous
//
#include <hip/hip_runtime.h>
#include <math.h>

typedef float fx4 __attribute__((ext_vector_type(4)));
typedef short bf8 __attribute__((ext_vector_type(8)));
typedef unsigned short us4 __attribute__((ext_vector_type(4)));

#define DEV __device__ __forceinline__

static constexpr int BB = 2;
static constexpr int SS = 1024;
static constexpr int II = 2048;
static constexpr int NSt = 16;
static constexpr int MR = BB * SS;   // 2048 rows
static constexpr int NC = 32;        // scan chunks
static constexpr int CL = SS / NC;   // 32 steps per chunk

DEV unsigned short f2bf(float f) {
  union { float f; unsigned u; } v; v.f = f;
  return (unsigned short)((v.u + 0x7FFFu + ((v.u >> 16) & 1u)) >> 16);
}

DEV float fsilu(float x) { return x / (1.f + __expf(-x)); }

DEV void gl2lds16(const unsigned short* g, unsigned short* l) {
  __builtin_amdgcn_global_load_lds(
      (const __attribute__((address_space(1))) unsigned int*)g,
      (__attribute__((address_space(3))) unsigned int*)l, 16, 0, 0);
}

// ---------- cast fp32 -> bf16 (contiguous, 4 elems/thread) ----------
__global__ void k_cast(const float* __restrict__ in, unsigned short* __restrict__ o, int n4) {
  int t = blockIdx.x * blockDim.x + threadIdx.x;
  if (t >= n4) return;
  fx4 v = *(const fx4*)(in + (size_t)t * 4);
  us4 r; r.x = f2bf(v.x); r.y = f2bf(v.y); r.z = f2bf(v.z); r.w = f2bf(v.w);
  *(us4*)(o + (size_t)t * 4) = r;
}

// ---------- transpose + cast: W[K][N] f32 -> Wt[N][K] bf16 ----------
template<int K, int N>
__global__ __launch_bounds__(256) void k_transpose_cast(const float* __restrict__ W,
                                                        unsigned short* __restrict__ Wt) {
  __shared__ float tile[64][65];
  int tk0 = blockIdx.y * 64, tn0 = blockIdx.x * 64;
  int t = threadIdx.x;
  int r = t >> 4, c4 = (t & 15) * 4;
#pragma unroll
  for (int q = 0; q < 4; ++q) {
    fx4 v = *(const fx4*)(W + (size_t)(tk0 + r + q * 16) * N + tn0 + c4);
    tile[r + q * 16][c4 + 0] = v.x;
    tile[r + q * 16][c4 + 1] = v.y;
    tile[r + q * 16][c4 + 2] = v.z;
    tile[r + q * 16][c4 + 3] = v.w;
  }
  __syncthreads();
#pragma unroll
  for (int q = 0; q < 4; ++q) {
    int nn = r + q * 16;
    us4 o;
    o.x = f2bf(tile[c4 + 0][nn]);
    o.y = f2bf(tile[c4 + 1][nn]);
    o.z = f2bf(tile[c4 + 2][nn]);
    o.w = f2bf(tile[c4 + 3][nn]);
    *(us4*)(Wt + (size_t)(tn0 + nn) * K + tk0 + c4) = o;
  }
}

// ---------- bf16 MFMA GEMM (m97 structure): C[M][N] = A[M][K] * Bt[N][K]^T ----
// Linear LDS [128][32] bf16, global_load_lds width-16 staging.
// EPI 0: plain f32 store.  EPI 1: softplus(acc + bias[col]).
template<int M, int N, int K, int EPI>
__global__ __launch_bounds__(256) void k_gemm(const unsigned short* __restrict__ A,
                                              const unsigned short* __restrict__ Bt,
                                              const float* __restrict__ bias,
                                              float* __restrict__ C) {
  __shared__ __align__(16) unsigned short As[128 * 32];
  __shared__ __align__(16) unsigned short Bs[128 * 32];
  const int t = threadIdx.x;
  const int bm0 = blockIdx.y * 128, bn0 = blockIdx.x * 128;
  const int w = t >> 6, l = t & 63;
  const int wm = (w >> 1) * 64, wn = (w & 1) * 64;
  const int lr = l & 15, lg = l >> 4;

  // staging coords: wave w stages rows [w*16, w*16+16) of each 64-row half.
  const int srow = w * 16 + (l >> 2);   // row within 64-row half
  const int skq = (l & 3) * 8;          // k element offset (8 bf16 = 16B)
  const unsigned short* gA0 = A + (size_t)(bm0 + srow) * K + skq;
  const unsigned short* gA1 = A + (size_t)(bm0 + 64 + srow) * K + skq;
  const unsigned short* gB0 = Bt + (size_t)(bn0 + srow) * K + skq;
  const unsigned short* gB1 = Bt + (size_t)(bn0 + 64 + srow) * K + skq;
  unsigned short* lA0 = As + w * 512;          // wave-uniform LDS bases
  unsigned short* lA1 = As + 2048 + w * 512;
  unsigned short* lB0 = Bs + w * 512;
  unsigned short* lB1 = Bs + 2048 + w * 512;

  fx4 acc[4][4] = {};

  for (int k0 = 0; k0 < K; k0 += 32) {
    gl2lds16(gA0 + k0, lA0);
    gl2lds16(gA1 + k0, lA1);
    gl2lds16(gB0 + k0, lB0);
    gl2lds16(gB1 + k0, lB1);
    __syncthreads();
    bf8 af[4], bg[4];
#pragma unroll
    for (int m = 0; m < 4; ++m) af[m] = *(const bf8*)(&As[(wm + m * 16 + lr) * 32 + lg * 8]);
#pragma unroll
    for (int n = 0; n < 4; ++n) bg[n] = *(const bf8*)(&Bs[(wn + n * 16 + lr) * 32 + lg * 8]);
#pragma unroll
    for (int m = 0; m < 4; ++m)
#pragma unroll
      for (int n = 0; n < 4; ++n)
        acc[m][n] = __builtin_amdgcn_mfma_f32_16x16x32_bf16(af[m], bg[n], acc[m][n], 0, 0, 0);
    __syncthreads();
  }
#pragma unroll
  for (int m = 0; m < 4; ++m) {
#pragma unroll
    for (int n = 0; n < 4; ++n) {
      int col = bn0 + wn + n * 16 + lr;
#pragma unroll
      for (int r = 0; r < 4; ++r) {
        int row = bm0 + wm + m * 16 + lg * 4 + r;
        float v = acc[m][n][r];
        if constexpr (EPI == 1) {
          float xx = v + bias[col];
          v = (xx > 20.f) ? xx : log1pf(__expf(xx));
        }
        C[(size_t)row * N + col] = v;
      }
    }
  }
}

// ---------- depthwise conv (k=3, pad 1 per batch) + silu ----------
__global__ void k_conv(const float* __restrict__ zx, const float* __restrict__ cw,
                       const float* __restrict__ cb, float* __restrict__ hf,
                       unsigned short* __restrict__ hb) {
  int idx = blockIdx.x * blockDim.x + threadIdx.x;  // MR * II/4 threads
  int i4 = idx & (II / 4 - 1);
  int r = idx >> 9;
  int s = r & (SS - 1);
  int i = i4 * 4;
  const float* base = zx + (size_t)r * (2 * II) + i;
  fx4 cur = *(const fx4*)(base);
  fx4 lf = {0.f, 0.f, 0.f, 0.f}, rt = {0.f, 0.f, 0.f, 0.f};
  if (s > 0)      lf = *(const fx4*)(base - 2 * II);
  if (s < SS - 1) rt = *(const fx4*)(base + 2 * II);
  fx4 hv; us4 hbv;
#pragma unroll
  for (int j = 0; j < 4; ++j) {
    float w0 = cw[(i + j) * 3 + 0], w1 = cw[(i + j) * 3 + 1], w2 = cw[(i + j) * 3 + 2];
    float c = lf[j] * w0 + cur[j] * w1 + rt[j] * w2 + cb[i + j];
    float h = fsilu(c);
    hv[j] = h; hbv[j] = f2bf(h);
  }
  *(fx4*)(hf + (size_t)r * II + i) = hv;
  *(us4*)(hb + (size_t)r * II + i) = hbv;
}

// ---------- B_mat = h @ W_state[:,16:32]  (one wave per row) ----------
__global__ __launch_bounds__(256) void k_state(const float* __restrict__ h,
                                               const float* __restrict__ Ws,
                                               float* __restrict__ Bm) {
  int wv = blockIdx.x * 4 + (threadIdx.x >> 6);
  int l = threadIdx.x & 63;
  int n = l & 15, ks = l >> 4;
  const float* hr = h + (size_t)wv * II;
  float acc = 0.f;
#pragma unroll 4
  for (int j = 0; j < II / 4; ++j) {
    int k = ks * (II / 4) + j;
    acc = fmaf(hr[k], Ws[k * (2 * NSt) + NSt + n], acc);
  }
  acc += __shfl_xor(acc, 16);
  acc += __shfl_xor(acc, 32);
  if (ks == 0) Bm[(size_t)wv * NSt + n] = acc;
}

// ---------- scan pass 1: per-chunk local scan; thread owns (b,c,i), 16 n-states in regs ----------
__global__ __launch_bounds__(256) void k_scan1(const float* __restrict__ dt, const float* __restrict__ h,
                        const float* __restrict__ Bm, const float* __restrict__ Alog,
                        float* __restrict__ me, float* __restrict__ pa) {
  __shared__ float BmL[CL * NSt];
  const int t = threadIdx.x;
  const int i = blockIdx.x * 256 + t;
  const int c = blockIdx.y, b = blockIdx.z;
  const int s0 = c * CL;
  if (t < CL * NSt / 4)
    ((fx4*)BmL)[t] = ((const fx4*)(Bm + (size_t)(b * SS + s0) * NSt))[t];
  __syncthreads();
  float a[16];
#pragma unroll
  for (int n = 0; n < 16; ++n) a[n] = -__expf(Alog[i * NSt + n]);
  float mem[16] = {}, pr[16];
#pragma unroll
  for (int n = 0; n < 16; ++n) pr[n] = 1.f;
  for (int q = 0; q < CL; ++q) {
    size_t ro = (size_t)(b * SS + s0 + q);
    float dtv = dt[ro * II + i];
    float hv = h[ro * II + i];
    float dth = dtv * hv;
#pragma unroll
    for (int n = 0; n < 16; ++n) {
      float dA = __expf(dtv * a[n]);
      mem[n] = fmaf(dA, mem[n], dth * BmL[q * NSt + n]);
      pr[n] *= dA;
    }
  }
  size_t o = (((size_t)b * NC + c) << 15) + ((size_t)i * 16);
#pragma unroll
  for (int j = 0; j < 4; ++j) {
    *(fx4*)(me + o + j * 4) = *(const fx4*)(mem + j * 4);
    *(fx4*)(pa + o + j * 4) = *(const fx4*)(pr + j * 4);
  }
}

// ---------- scan pass 2: carry combine across chunks ----------
__global__ void k_scan2(const float* __restrict__ me, const float* __restrict__ pa,
                        float* __restrict__ carry) {
  int idx = blockIdx.x * blockDim.x + threadIdx.x;  // BB*II*16 = 65536
  int b = idx >> 15;
  int rem = idx & 32767;
  float cur = 0.f;
  for (int c = 0; c < NC; ++c) {
    size_t o = (((size_t)b * NC + c) << 15) + rem;
    carry[o] = cur;
    cur = fmaf(pa[o], cur, me[o]);
  }
}

// ---------- scan pass 3: replay with carry; y = sum_n mem + skip*h; fuse gate ----------
__global__ __launch_bounds__(256) void k_scan3(const float* __restrict__ dt, const float* __restrict__ h,
                        const float* __restrict__ Bm, const float* __restrict__ Alog,
                        const float* __restrict__ carry, const float* __restrict__ skip,
                        const float* __restrict__ zx, unsigned short* __restrict__ yg) {
  __shared__ float BmL[CL * NSt];
  const int t = threadIdx.x;
  const int i = blockIdx.x * 256 + t;
  const int c = blockIdx.y, b = blockIdx.z;
  const int s0 = c * CL;
  if (t < CL * NSt / 4)
    ((fx4*)BmL)[t] = ((const fx4*)(Bm + (size_t)(b * SS + s0) * NSt))[t];
  __syncthreads();
  float a[16], mem[16];
#pragma unroll
  for (int n = 0; n < 16; ++n) a[n] = -__expf(Alog[i * NSt + n]);
  size_t o = (((size_t)b * NC + c) << 15) + ((size_t)i * 16);
#pragma unroll
  for (int j = 0; j < 4; ++j) *(fx4*)(mem + j * 4) = *(const fx4*)(carry + o + j * 4);
  const float sk = skip[i];
  for (int q = 0; q < CL; ++q) {
    size_t ro = (size_t)(b * SS + s0 + q);
    float dtv = dt[ro * II + i];
    float hv = h[ro * II + i];
    float dth = dtv * hv;
    float y = 0.f;
#pragma unroll
    for (int n = 0; n < 16; ++n) {
      float dA = __expf(dtv * a[n]);
      mem[n] = fmaf(dA, mem[n], dth * BmL[q * NSt + n]);
      y += mem[n];
    }
    y += sk * hv;
    float g = zx[ro * (2 * II) + II + i];
    yg[ro * II + i] = f2bf(y * fsilu(g));
  }
}

extern "C" void kernel_launch(void* const* d_in, const int* in_sizes, int n_in,
                              void* d_out, int out_size, void* d_ws, size_t ws_size,
                              hipStream_t stream) {
  const float* x      = (const float*)d_in[0];
  const float* W_in   = (const float*)d_in[1];
  const float* conv_w = (const float*)d_in[2];
  const float* conv_b = (const float*)d_in[3];
  const float* W_state= (const float*)d_in[4];
  const float* W_time = (const float*)d_in[5];
  const float* b_time = (const float*)d_in[6];
  const float* A_log  = (const float*)d_in[7];
  const float* skip   = (const float*)d_in[8];
  const float* W_out  = (const float*)d_in[9];
  float* out = (float*)d_out;

  char* p = (char*)d_ws;
  const size_t MB = 1u << 20;
  unsigned short* W_in_t   = (unsigned short*)(p + 0);        // 8 MiB  [reused: me]
  unsigned short* W_time_t = (unsigned short*)(p + 8 * MB);   // 8 MiB  [reused: carry]
  unsigned short* W_out_t  = (unsigned short*)(p + 16 * MB);  // 4 MiB
  unsigned short* x_bf     = (unsigned short*)(p + 20 * MB);  // 4 MiB
  float*          zx       = (float*)(p + 24 * MB);           // 32 MiB
  float*          hf       = (float*)(p + 56 * MB);           // 16 MiB
  unsigned short* h_bf     = (unsigned short*)(p + 72 * MB);  // 8 MiB  [reused: yg]
  float*          dtb      = (float*)(p + 80 * MB);           // 16 MiB
  float*          Bm       = (float*)(p + 96 * MB);           // 128 KiB
  float*          pa       = (float*)(p + 97 * MB);           // 8 MiB (prodA)  -> total 105 MiB
  float* me    = (float*)W_in_t;    // alias, live after GEMM1 is done with W_in_t
  float* carry = (float*)W_time_t;  // alias, live after dt-GEMM is done with W_time_t
  unsigned short* yg = h_bf;        // alias, live after dt-GEMM is done with h_bf

  // 1) casts / transposes
  k_cast<<<dim3((MR * 1024 / 4 + 255) / 256), 256, 0, stream>>>(x, x_bf, MR * 1024 / 4);
  k_transpose_cast<1024, 4096><<<dim3(64, 16), 256, 0, stream>>>(W_in, W_in_t);
  k_transpose_cast<2048, 2048><<<dim3(32, 32), 256, 0, stream>>>(W_time, W_time_t);
  k_transpose_cast<2048, 1024><<<dim3(16, 32), 256, 0, stream>>>(W_out, W_out_t);

  // 2) zx = x @ W_in   [2048 x 4096] f32
  k_gemm<2048, 4096, 1024, 0><<<dim3(32, 16), 256, 0, stream>>>(x_bf, W_in_t, nullptr, zx);

  // 3) conv + silu -> h (f32 + bf16)
  k_conv<<<dim3(MR * (II / 4) / 256), 256, 0, stream>>>(zx, conv_w, conv_b, hf, h_bf);

  // 4) B_mat = h @ W_state[:,16:32]
  k_state<<<dim3(MR / 4), 256, 0, stream>>>(hf, W_state, Bm);

  // 5) dt = softplus(h @ W_time + b_time)
  k_gemm<2048, 2048, 2048, 1><<<dim3(16, 16), 256, 0, stream>>>(h_bf, W_time_t, b_time, dtb);

  // 6) chunked selective scan
  k_scan1<<<dim3(II / 256, NC, BB), 256, 0, stream>>>(dtb, hf, Bm, A_log, me, pa);
  k_scan2<<<dim3(BB * II * 16 / 256), 256, 0, stream>>>(me, pa, carry);
  k_scan3<<<dim3(II / 256, NC, BB), 256, 0, stream>>>(dtb, hf, Bm, A_log, carry, skip, zx, yg);

  // 7) out = (y * silu(gate)) @ W_out
  k_gemm<2048, 1024, 2048, 0><<<dim3(8, 16), 256, 0, stream>>>(yg, W_out_t, nullptr, out);
}